// Round 2
// baseline (785.874 us; speedup 1.0000x reference)
//
#include <hip/hip_runtime.h>
#include <math.h>

// MMD, Gaussian kernel, bandwidth=512. X:[8192,512] Y:[8192,512] fp32.
// S_AB = sum_ij exp(-||a_i-b_j||^2/512); final combine emulates the
// reference's fp32 logsumexp->exp->combine path (see finalize_kernel).
//
// Architecture (validated R9-R11): fp16 single-product MFMA S-pass (S needs
// << 1 fp32 lse cell = 17 units of 9.1e6) + bit-exact reproduction of the
// R5 bf16-split 3-product d2 min for m (lse cell shifts with m at sub-ulp
// granularity -> m must be the exact winning bits; XX/YY via 32x32 diag
// self-tiles, XY via banded refine).
// Round-13: counted-vmcnt pipeline (T3/T4): prefetch stays in flight across
// both barriers (vmcnt(N), never 0 in-loop). Gave +5% only: occupancy is
// register-capped (acc 128 AGPR + 120 arch = 248 -> 2 waves/SIMD) and the
// 2 lockstep phase-streams leave the pipes serialized (interval 6560cy ~=
// MFMA 2066 + vmem 2000 + ds_read 1536 summed, not overlapped).
// Round-14: 3 waves/SIMD. (1) A staged via global_load_lds too (deletes the
// 64-VGPR Af array AND the 2x-duplicated A vector-load traffic; fragment
// bits unchanged). (2) 2-kstep buffers: LDS 2x24KB+norms ~= 50KB -> 3
// blocks/CU. (3) __launch_bounds__(256,3) caps total regs at 170.
// Window = 6 DMA/wave/interval -> vmcnt(6). K-steps remain sequential
// 0..31, per-kstep MFMA order unchanged -> bit-identical to R12/R13.

#define D      512
#define BTM    128
#define BTN    256
#define BK     16
#define KSTEPS (D / BK)

// 16B-unit offsets in the XY refine kernel's LDS (R5 layout [point*2+khalf])
#define AHI 0
#define ALO 256
#define BHI 512
#define BLO 1024

typedef _Float16 half8 __attribute__((ext_vector_type(8)));
typedef __attribute__((ext_vector_type(8)))  short  short8;   // 8 bf16
typedef __attribute__((ext_vector_type(16))) float  f32x16;   // 32x32 acc

union U4H8 { uint4 u; half8 h; };
union U4S8 { uint4 u; short8 s; };

__device__ __forceinline__ unsigned short bf16_rne(float x) {
    unsigned u = __float_as_uint(x);
    return (unsigned short)((u + 0x7fffu + ((u >> 16) & 1u)) >> 16);
}
__device__ __forceinline__ float bf16_f32(unsigned short b) {
    return __uint_as_float(((unsigned)b) << 16);
}
__device__ __forceinline__ void split8(const float v[8], uint4& hi, uint4& lo) {
    unsigned h[8], l[8];
    #pragma unroll
    for (int j = 0; j < 8; j++) {
        unsigned short bh = bf16_rne(v[j]);
        float r = v[j] - bf16_f32(bh);          // exact (Sterbenz)
        unsigned short bl = bf16_rne(r);
        h[j] = bh; l[j] = bl;
    }
    hi.x = h[0] | (h[1] << 16); hi.y = h[2] | (h[3] << 16);
    hi.z = h[4] | (h[5] << 16); hi.w = h[6] | (h[7] << 16);
    lo.x = l[0] | (l[1] << 16); lo.y = l[2] | (l[3] << 16);
    lo.z = l[4] | (l[5] << 16); lo.w = l[6] | (l[7] << 16);
}

// async global->LDS, 16B per lane
__device__ __forceinline__ void lds16(const uint4* g, uint4* l) {
    __builtin_amdgcn_global_load_lds(
        (const __attribute__((address_space(1))) void*)g,
        (__attribute__((address_space(3))) void*)(unsigned int)(uintptr_t)(void*)l,
        16, 0, 0);
}

__global__ void init_kernel(double* accum, unsigned* minkey) {
    if (threadIdx.x < 3) accum[threadIdx.x] = 0.0;
    if (threadIdx.x < 4) minkey[threadIdx.x] = 0xFFFFFFFFu;
}

// fp16 convert: src[npts][512] fp32 -> [kstep][p>>5][khalf][p&31] 16B units
__global__ __launch_bounds__(256)
void convert_h_kernel(const float* __restrict__ X, const float* __restrict__ Y,
                      uint4* __restrict__ Xh, uint4* __restrict__ Yh, int npts) {
    const float* src = blockIdx.z ? Y : X;
    uint4*       dst = blockIdx.z ? Yh : Xh;
    const int ks = blockIdx.y;
    const int p  = blockIdx.x * 256 + threadIdx.x;
    if (p >= npts) return;
    const float* s = src + (size_t)p * D + ks * BK;
    float v[16];
    *(float4*)&v[0]  = *(const float4*)(s);
    *(float4*)&v[4]  = *(const float4*)(s + 4);
    *(float4*)&v[8]  = *(const float4*)(s + 8);
    *(float4*)&v[12] = *(const float4*)(s + 12);
    U4H8 a, b;
    #pragma unroll
    for (int j = 0; j < 8; j++) { a.h[j] = (_Float16)v[j]; b.h[j] = (_Float16)v[8 + j]; }
    size_t u = (size_t)ks * npts * 2 + (size_t)(p >> 5) * 64 + (p & 31);
    dst[u] = a.u; dst[u + 32] = b.u;
}

__global__ __launch_bounds__(256)
void row_norms_kernel(const float* __restrict__ X, const float* __restrict__ Y,
                      float* __restrict__ X2, float* __restrict__ Y2, int N, int M) {
    const int wave = threadIdx.x >> 6;
    const int lane = threadIdx.x & 63;
    const int row  = blockIdx.x * 4 + wave;
    const float* src; float* dst; int r;
    if (row < N)          { src = X; dst = X2; r = row; }
    else if (row < N + M) { src = Y; dst = Y2; r = row - N; }
    else return;
    const float* p = src + (size_t)r * D;
    float s = 0.f;
    #pragma unroll
    for (int c = 0; c < D; c += 64) {
        float v = p[c + lane];
        s = fmaf(v, v, s);
    }
    #pragma unroll
    for (int off = 32; off > 0; off >>= 1) s += __shfl_down(s, off);
    if (lane == 0) dst[r] = s;
}

__device__ inline unsigned float_key(float f) {
    unsigned u = __float_as_uint(f);
    return (u & 0x80000000u) ? ~u : (u | 0x80000000u);
}
__device__ inline float key_float(unsigned k) {
    return __uint_as_float((k & 0x80000000u) ? (k ^ 0x80000000u) : ~k);
}

// ---- XX/YY m: R5-bit-exact diag d2 via 32x32 self-tiles (fused X+Y) ------
__global__ __launch_bounds__(256)
void diag_min_bits_kernel(const float* __restrict__ X, const float* __restrict__ Y,
                          const float* __restrict__ X2, const float* __restrict__ Y2,
                          unsigned* __restrict__ minkey, int ngx) {
    int b = blockIdx.x;
    const float *src, *n2; int zidx;
    if (b < ngx) { src = X; n2 = X2; zidx = 0; }
    else         { src = Y; n2 = Y2; zidx = 2; b -= ngx; }

    const int tid  = threadIdx.x;
    const int wave = tid >> 6, lane = tid & 63;
    const int grp  = b * 4 + wave;                // 32-point group id
    const int fp   = lane & 31, fh = lane >> 5;
    const int pt   = grp * 32 + fp;
    const float* s = src + (size_t)pt * D + fh * 8;

    f32x16 acc;
    #pragma unroll
    for (int i = 0; i < 16; i++) acc[i] = 0.f;

    for (int ks = 0; ks < KSTEPS; ks++) {
        float v[8];
        *(float4*)&v[0] = *(const float4*)(s + ks * BK);
        *(float4*)&v[4] = *(const float4*)(s + ks * BK + 4);
        U4S8 hi, lo;
        split8(v, hi.u, lo.u);
        short8 ah = hi.s, al = lo.s;
        // R5 order: hh, h*lB, lA*h (A-frag == B-frag here)
        acc = __builtin_amdgcn_mfma_f32_32x32x16_bf16(ah, ah, acc, 0, 0, 0);
        acc = __builtin_amdgcn_mfma_f32_32x32x16_bf16(ah, al, acc, 0, 0, 0);
        acc = __builtin_amdgcn_mfma_f32_32x32x16_bf16(al, ah, acc, 0, 0, 0);
    }

    float dmin = 1e30f;
    if (fh == ((fp >> 2) & 1)) {
        int r = (fp & 3) + 4 * (fp >> 3);
        float av = acc[r];
        float rn = n2[pt];
        float cn = rn;
        float d2 = rn + cn - 2.0f * av;           // exact: contraction-safe
        dmin = d2;
    }
    #pragma unroll
    for (int off = 32; off > 0; off >>= 1) dmin = fminf(dmin, __shfl_down(dmin, off));
    __shared__ float wm[4];
    __shared__ int   wz[4];
    if (lane == 0) { wm[wave] = dmin; wz[wave] = zidx; }
    __syncthreads();
    if (tid == 0)
        atomicMin(&minkey[wz[0]],
                  float_key(fminf(fminf(wm[0], wm[1]), fminf(wm[2], wm[3]))));
}

// ---------- fp16 S-pass: grid (64,32,3): z=0 XX (sym), 1 XY, 2 YY ----------
// LDS per 2-kstep buffer: [kstep j][A 256u | B 512u] (768 uint4 = 12 KB).
// Both A and B staged via global_load_lds -> no Af VGPR array, no duplicate
// A vector loads. 2 bufs x 24 KB + norms ~= 50 KB -> 3 blocks/CU;
// __launch_bounds__(256,3) caps total regs (128 acc AGPR + ~42 arch).
__global__ __launch_bounds__(256, 3)
void pair_exp_sum_kernel(const uint4* __restrict__ Xh, const uint4* __restrict__ Yh,
                         const float* __restrict__ X2, const float* __restrict__ Y2,
                         double* __restrict__ accum, float* __restrict__ bmin,
                         int N, int M) {
    const int z = blockIdx.z;
    const uint4 *Ah, *Bh; const float *An, *Bn; bool sym; int na, nb;
    if (z == 0)      { Ah = Xh; Bh = Xh; An = X2; Bn = X2; sym = true;  na = N; nb = N; }
    else if (z == 1) { Ah = Xh; Bh = Yh; An = X2; Bn = Y2; sym = false; na = N; nb = M; }
    else             { Ah = Yh; Bh = Yh; An = Y2; Bn = Y2; sym = true;  na = M; nb = M; }
    const int bi = blockIdx.x, bj = blockIdx.y;
    if (sym && (2 * bj + 1) < bi) return;        // both 128-col halves below diag

    __shared__ uint4  smem[2][1536];             // 2 bufs x 24 KB (2 ksteps each)
    __shared__ float  smN[BTM + BTN];
    __shared__ double wsum[4];
    __shared__ float  wmin[4];

    const int tid  = threadIdx.x;
    const int wave = tid >> 6, lane = tid & 63;
    const int wy = wave >> 1, wx = wave & 1;     // 2x2 waves, each 64x128
    const int row0 = bi * BTM, col0 = bj * BTN;

    if (tid < BTM) smN[tid] = An[row0 + tid];
    smN[BTM + tid] = Bn[col0 + tid];

    const int wl = wave * 64 + lane;
    const size_t strideA = (size_t)na * 2;       // 16B units per kstep
    const size_t strideB = (size_t)nb * 2;
    const uint4* gA0 = Ah + (size_t)(row0 >> 5) * 64 + wl;   // wave's 64-unit slice of A
    const uint4* gB0 = Bh + (size_t)(col0 >> 5) * 64 + wl;
    const uint4* gB1 = gB0 + 256;

    f32x16 acc[2][4];
    #pragma unroll
    for (int g = 0; g < 2; g++)
        #pragma unroll
        for (int c = 0; c < 4; c++)
            #pragma unroll
            for (int i = 0; i < 16; i++) acc[g][c][i] = 0.f;

    // stage TWO k-steps into one buffer; kstep j at unit j*768: A@0, B@256
    auto stage2 = [&](int buf, int ks) {
        #pragma unroll
        for (int j = 0; j < 2; j++) {
            lds16(gA0 + (size_t)(ks + j) * strideA, &smem[buf][j * 768 + wl]);
            lds16(gB0 + (size_t)(ks + j) * strideB, &smem[buf][j * 768 + 256 + wl]);
            lds16(gB1 + (size_t)(ks + j) * strideB, &smem[buf][j * 768 + 512 + wl]);
        }
    };
    auto computeK = [&](const uint4* base) {     // one kstep: A@0, B@256
        const half8* p = (const half8*)base;
        half8 ah[2], bh[4];
        #pragma unroll
        for (int g = 0; g < 2; g++) ah[g] = p[(2 * wy + g) * 64 + lane];
        #pragma unroll
        for (int c = 0; c < 4; c++) bh[c] = p[256 + (4 * wx + c) * 64 + lane];
        #pragma unroll
        for (int g = 0; g < 2; g++)
            #pragma unroll
            for (int c = 0; c < 4; c++)
                acc[g][c] = __builtin_amdgcn_mfma_f32_32x32x16_f16(ah[g], bh[c], acc[g][c], 0, 0, 0);
    };

    // Counted-vmcnt schedule. Window invariant: each iteration issues exactly
    // 6 DMA ops per wave ("memory"-fenced) -> at s_waitcnt vmcnt(6) the
    // previous window's 6 are the FIFO-oldest outstanding, so they (and only
    // they) are drained. Current window's prefetch stays in flight across
    // both barriers.
    stage2(0, 0);

    #pragma unroll
    for (int it = 1; it < KSTEPS / 2; it++) {    // 15 intervals
        stage2(it & 1, 2 * it);                  // prefetch next pair (6 DMA)
        asm volatile("s_waitcnt vmcnt(6)" ::: "memory");    // prev pair landed (self)
        __builtin_amdgcn_s_barrier();                       // ... for all waves
        __builtin_amdgcn_sched_barrier(0);                  // pin ds_reads below
        const int pb = (it - 1) & 1;
        computeK(&smem[pb][0]);                  // ksteps 2(it-1), 2(it-1)+1
        computeK(&smem[pb][768]);
        asm volatile("s_waitcnt lgkmcnt(0)" ::: "memory");  // my ds_reads retired
        __builtin_amdgcn_s_barrier();                       // buffer pb free for all
    }
    asm volatile("s_waitcnt vmcnt(0)" ::: "memory");        // last pair landed
    __builtin_amdgcn_s_barrier();
    __builtin_amdgcn_sched_barrier(0);
    computeK(&smem[1][0]);                       // ksteps 30, 31
    computeK(&smem[1][768]);

    float wgt = 1.f;
    if (sym) {
        int cblk = 2 * bj + wx;
        wgt = (cblk > bi) ? 2.f : (cblk == bi ? 1.f : 0.f);
    }

    // C/D layout (m74/m101): col=lane&31, row=(reg&3)+8*(reg>>2)+4*(lane>>5)
    const int fp = lane & 31, fh = lane >> 5;
    double s = 0.0;
    float dmin = 1e30f;
    if (wgt != 0.f) {
        const float* rowN = &smN[64 * wy];
        const float* colN = &smN[BTM + 128 * wx];
        const float kC = -0.0028177637517362567f;   // -log2(e)/512
        #pragma unroll
        for (int g = 0; g < 2; g++)
            #pragma unroll
            for (int c = 0; c < 4; c++) {
                float cn = colN[32 * c + fp];
                float rs = 0.f;
                #pragma unroll
                for (int r = 0; r < 16; r++) {
                    int r32 = (r & 3) + 8 * (r >> 2) + 4 * fh;
                    float d2 = rowN[32 * g + r32] + cn - 2.0f * acc[g][c][r];
                    dmin = fminf(dmin, d2);
                    rs += exp2f(d2 * kC);            // v_exp_f32; args in [-4.2,0]
                }
                s += (double)rs;
            }
        s *= (double)wgt;
    }

    #pragma unroll
    for (int off = 32; off > 0; off >>= 1) {
        s += __shfl_down(s, off);
        dmin = fminf(dmin, __shfl_down(dmin, off));
    }
    if (lane == 0) { wsum[wave] = s; wmin[wave] = dmin; }
    __syncthreads();
    if (tid == 0) {
        atomicAdd(&accum[z], wsum[0] + wsum[1] + wsum[2] + wsum[3]);
        if (z == 1)                              // noisy (+-~0.05) block min
            bmin[bi * gridDim.y + bj] = fminf(fminf(wmin[0], wmin[1]),
                                              fminf(wmin[2], wmin[3]));
    }
}

__global__ __launch_bounds__(256)
void xy_gmin_kernel(const float* __restrict__ bmin, float* __restrict__ gmin, int nblk) {
    float m = 1e30f;
    for (int i = threadIdx.x; i < nblk; i += 256) m = fminf(m, bmin[i]);
    #pragma unroll
    for (int off = 32; off > 0; off >>= 1) m = fminf(m, __shfl_down(m, off));
    __shared__ float wm[4];
    if ((threadIdx.x & 63) == 0) wm[threadIdx.x >> 6] = m;
    __syncthreads();
    if (threadIdx.x == 0) gmin[0] = fminf(fminf(wm[0], wm[1]), fminf(wm[2], wm[3]));
}

// ---------- XY refine: R5-bit-exact bf16-split 3-product d2 min -----------
// 1024 threads / 16 waves; wave w owns row-group gy=w&3 (32 rows) and col
// groups 2*(w>>2), 2*(w>>2)+1. Per-accumulator k-chain (hh,hl,lh per kstep,
// ks 0..31) identical to R5 -> same d2 bits; ~4x less serial latency.
__global__ __launch_bounds__(1024)
void refine_min_kernel(const float* __restrict__ A, const float* __restrict__ B,
                       const float* __restrict__ An, const float* __restrict__ Bn,
                       const float* __restrict__ bmin, const float* __restrict__ gmin,
                       unsigned* __restrict__ minkey, int zidx) {
    const int bi = blockIdx.x;
    const int bj = blockIdx.y;
    if (!(bmin[bi * gridDim.y + bj] < gmin[0] + 0.5f)) return;
    const int row0 = bi * BTM, col0 = bj * BTN;

    __shared__ uint4 smem[1536];                 // Ahi|Alo|Bhi|Blo (R5 layout)
    __shared__ float smN[BTM + BTN];
    __shared__ float wmin[16];

    const int tid  = threadIdx.x;
    const int wave = tid >> 6, lane = tid & 63;
    const int gy = wave & 3, cg0 = 2 * (wave >> 2);
    if (tid < BTM) smN[tid] = An[row0 + tid];
    if (tid < BTN) smN[BTM + tid] = Bn[col0 + tid];

    const int fp = lane & 31, fh = lane >> 5;
    const int au = (32 * gy + fp) * 2 + fh;
    int bu[2];
    #pragma unroll
    for (int c = 0; c < 2; c++) bu[c] = (32 * (cg0 + c) + fp) * 2 + fh;

    f32x16 acc[2];
    #pragma unroll
    for (int c = 0; c < 2; c++)
        #pragma unroll
        for (int i = 0; i < 16; i++) acc[c][i] = 0.f;

    for (int ks = 0; ks < KSTEPS; ks++) {
        __syncthreads();                         // prev-step LDS reads done
        if (tid < 256) {                         // A: unit tid
            const float* s = A + (size_t)(row0 + (tid >> 1)) * D + ks * BK + (tid & 1) * 8;
            float v[8];
            *(float4*)&v[0] = *(const float4*)s;
            *(float4*)&v[4] = *(const float4*)(s + 4);
            uint4 hi, lo; split8(v, hi, lo);
            smem[AHI + tid] = hi; smem[ALO + tid] = lo;
        } else if (tid < 768) {                  // B: unit tid-256
            int u = tid - 256;
            const float* s = B + (size_t)(col0 + (u >> 1)) * D + ks * BK + (u & 1) * 8;
            float v[8];
            *(float4*)&v[0] = *(const float4*)s;
            *(float4*)&v[4] = *(const float4*)(s + 4);
            uint4 hi, lo; split8(v, hi, lo);
            smem[BHI + u] = hi; smem[BLO + u] = lo;
        }
        __syncthreads();
        {   // per-acc chain: hh, hl, lh (matches R5 acc[g][c] chain order)
            const short8* p = (const short8*)&smem[0];
            short8 ah = p[AHI + au], al = p[ALO + au];
            short8 bh[2], bl[2];
            #pragma unroll
            for (int c = 0; c < 2; c++) { bh[c] = p[BHI + bu[c]]; bl[c] = p[BLO + bu[c]]; }
            #pragma unroll
            for (int c = 0; c < 2; c++)
                acc[c] = __builtin_amdgcn_mfma_f32_32x32x16_bf16(ah, bh[c], acc[c], 0, 0, 0);
            #pragma unroll
            for (int c = 0; c < 2; c++)
                acc[c] = __builtin_amdgcn_mfma_f32_32x32x16_bf16(ah, bl[c], acc[c], 0, 0, 0);
            #pragma unroll
            for (int c = 0; c < 2; c++)
                acc[c] = __builtin_amdgcn_mfma_f32_32x32x16_bf16(al, bh[c], acc[c], 0, 0, 0);
        }
    }

    float dmin = 1e30f;
    const float* rowN = &smN[32 * gy];
    #pragma unroll
    for (int c = 0; c < 2; c++) {
        float cn = smN[BTM + 32 * (cg0 + c) + fp];
        #pragma unroll
        for (int r = 0; r < 16; r++) {
            int r32 = (r & 3) + 8 * (r >> 2) + 4 * fh;
            float d2 = rowN[r32] + cn - 2.0f * acc[c][r];
            dmin = fminf(dmin, d2);
        }
    }

    #pragma unroll
    for (int off = 32; off > 0; off >>= 1) dmin = fminf(dmin, __shfl_down(dmin, off));
    if (lane == 0) wmin[wave] = dmin;
    __syncthreads();
    if (tid == 0) {
        float m = wmin[0];
        #pragma unroll
        for (int w = 1; w < 16; w++) m = fminf(m, wmin[w]);
        atomicMin(&minkey[zidx], float_key(m));
    }
}

__global__ void finalize_kernel(const double* __restrict__ accum,
                                const unsigned* __restrict__ minkey,
                                float* __restrict__ out, int N, int M) {
    if (threadIdx.x == 0 && blockIdx.x == 0) {
        float Sp[3];
        #pragma unroll
        for (int z = 0; z < 3; z++) {
            float m = key_float(minkey[z]) * (-1.0f / 512.0f);
            double Sshift = accum[z] * exp(-(double)m);
            float r = (float)log(Sshift);        // correctly-rounded f32 log
            float lse = r + m;                   // fp32 add, as jax
            Sp[z] = (float)exp((double)lse);     // correctly-rounded f32 exp
        }
        float nf  = (float)N, mf = (float)M;
        float nn1 = (float)((double)N * (double)(N - 1));
        float mm1 = (float)((double)M * (double)(M - 1));
        float nm  = (float)((double)N * (double)M);
        float xx = (Sp[0] - nf) / nn1;
        float xy =  Sp[1]       / nm;
        float yy = (Sp[2] - mf) / mm1;
        out[0] = xx - 2.0f * xy + yy;
    }
}

extern "C" void kernel_launch(void* const* d_in, const int* in_sizes, int n_in,
                              void* d_out, int out_size, void* d_ws, size_t ws_size,
                              hipStream_t stream) {
    const float* X = (const float*)d_in[0];
    const float* Y = (const float*)d_in[1];
    const int N = in_sizes[0] / D;
    const int M = in_sizes[1] / D;
    const int gx = N / BTM, gy = M / BTN;        // 64 x 32

    double*   accum  = (double*)d_ws;
    unsigned* minkey = (unsigned*)((char*)d_ws + 32);
    float*    gmin   = (float*)((char*)d_ws + 48);
    float*    X2     = (float*)((char*)d_ws + 64);
    float*    Y2     = X2 + N;
    float*    bmin   = Y2 + M;
    size_t off = (64 + (size_t)(N + M) * 4 + (size_t)gx * gy * 4 + 255) & ~(size_t)255;
    size_t asz = (size_t)N * D * 2;
    uint4* Xh = (uint4*)((char*)d_ws + off);
    uint4* Yh = (uint4*)((char*)d_ws + off + asz);

    init_kernel<<<1, 64, 0, stream>>>(accum, minkey);

    row_norms_kernel<<<(N + M + 3) / 4, 256, 0, stream>>>(X, Y, X2, Y2, N, M);
    convert_h_kernel<<<dim3((N + 255) / 256, KSTEPS, 2), 256, 0, stream>>>(X, Y, Xh, Yh, N);

    diag_min_bits_kernel<<<N / 128 + M / 128, 256, 0, stream>>>(X, Y, X2, Y2, minkey, N / 128);

    dim3 grid(gx, gy, 3);
    pair_exp_sum_kernel<<<grid, 256, 0, stream>>>(Xh, Yh, X2, Y2, accum, bmin, N, M);

    xy_gmin_kernel<<<1, 256, 0, stream>>>(bmin, gmin, gx * gy);
    refine_min_kernel<<<dim3(gx, gy), 1024, 0, stream>>>(X, Y, X2, Y2, bmin, gmin,
                                                         minkey, 1);

    finalize_kernel<<<1, 64, 0, stream>>>(accum, minkey, (float*)d_out, N, M);
}

// Round 3
// 315.798 us; speedup vs baseline: 2.4885x; 2.4885x over previous
//
#include <hip/hip_runtime.h>
#include <math.h>

// MMD, Gaussian kernel, bandwidth=512. X:[8192,512] Y:[8192,512] fp32.
// S_AB = sum_ij exp(-||a_i-b_j||^2/512); final combine emulates the
// reference's fp32 logsumexp->exp->combine path (see finalize_kernel).
//
// Architecture (validated R9-R11): fp16 single-product MFMA S-pass (S needs
// << 1 fp32 lse cell = 17 units of 9.1e6) + bit-exact reproduction of the
// R5 bf16-split 3-product d2 min for m (lse cell shifts with m at sub-ulp
// granularity -> m must be the exact winning bits; XX/YY via 32x32 diag
// self-tiles, XY via banded refine).
// Round-13: counted-vmcnt pipeline (vmcnt(N), never 0 in-loop): +5% only;
// 2 waves/SIMD (acc 128 + arch 120) leave pipes serialized (kstep 1640cy
// vs MFMA 516 + LDS ~575 + vmem ~240 -> poor overlap).
// Round-14 FAILED: __launch_bounds__(256,3) with acc=128 -> compiler spilled
// accumulators (WRITE_SIZE 150KB -> 1.5GB scratch), 4x regression. Lesson:
// occupancy must come from a SMALLER acc, not a register cap.
// Round-15: pair kernel re-tiled to 128x128 blocks, 4 waves of 64x64
// (acc[2][2]=64 regs + ~56 arch = ~120 <= 128 -> __launch_bounds__(256,4)
// is feasible, 4 waves/SIMD). A and B both DMA-staged, 2-kstep dbuf =
// 32KB LDS -> 4 blocks/CU. Uniform 4-DMA/wave windows -> vmcnt(4).
// Sym lower-triangle blocks early-return (R13 burned MFMAs on wgt=0
// halves). Per-cell MFMA chains stay ks=0..31 sequential on identical
// fragment bits -> S and all d2/min bits unchanged; bmin granularity is
// now 128 cols (refine gates on min of 2 entries -> identical decisions).

#define D      512
#define BTM    128
#define BTN    256   // refine-kernel tile (unchanged)
#define BTNP   128   // pair-kernel tile cols
#define BK     16
#define KSTEPS (D / BK)

// 16B-unit offsets in the XY refine kernel's LDS (R5 layout [point*2+khalf])
#define AHI 0
#define ALO 256
#define BHI 512
#define BLO 1024

typedef _Float16 half8 __attribute__((ext_vector_type(8)));
typedef __attribute__((ext_vector_type(8)))  short  short8;   // 8 bf16
typedef __attribute__((ext_vector_type(16))) float  f32x16;   // 32x32 acc

union U4H8 { uint4 u; half8 h; };
union U4S8 { uint4 u; short8 s; };

__device__ __forceinline__ unsigned short bf16_rne(float x) {
    unsigned u = __float_as_uint(x);
    return (unsigned short)((u + 0x7fffu + ((u >> 16) & 1u)) >> 16);
}
__device__ __forceinline__ float bf16_f32(unsigned short b) {
    return __uint_as_float(((unsigned)b) << 16);
}
__device__ __forceinline__ void split8(const float v[8], uint4& hi, uint4& lo) {
    unsigned h[8], l[8];
    #pragma unroll
    for (int j = 0; j < 8; j++) {
        unsigned short bh = bf16_rne(v[j]);
        float r = v[j] - bf16_f32(bh);          // exact (Sterbenz)
        unsigned short bl = bf16_rne(r);
        h[j] = bh; l[j] = bl;
    }
    hi.x = h[0] | (h[1] << 16); hi.y = h[2] | (h[3] << 16);
    hi.z = h[4] | (h[5] << 16); hi.w = h[6] | (h[7] << 16);
    lo.x = l[0] | (l[1] << 16); lo.y = l[2] | (l[3] << 16);
    lo.z = l[4] | (l[5] << 16); lo.w = l[6] | (l[7] << 16);
}

// async global->LDS, 16B per lane
__device__ __forceinline__ void lds16(const uint4* g, uint4* l) {
    __builtin_amdgcn_global_load_lds(
        (const __attribute__((address_space(1))) void*)g,
        (__attribute__((address_space(3))) void*)(unsigned int)(uintptr_t)(void*)l,
        16, 0, 0);
}

__global__ void init_kernel(double* accum, unsigned* minkey) {
    if (threadIdx.x < 3) accum[threadIdx.x] = 0.0;
    if (threadIdx.x < 4) minkey[threadIdx.x] = 0xFFFFFFFFu;
}

// fp16 convert: src[npts][512] fp32 -> [kstep][p>>5][khalf][p&31] 16B units
__global__ __launch_bounds__(256)
void convert_h_kernel(const float* __restrict__ X, const float* __restrict__ Y,
                      uint4* __restrict__ Xh, uint4* __restrict__ Yh, int npts) {
    const float* src = blockIdx.z ? Y : X;
    uint4*       dst = blockIdx.z ? Yh : Xh;
    const int ks = blockIdx.y;
    const int p  = blockIdx.x * 256 + threadIdx.x;
    if (p >= npts) return;
    const float* s = src + (size_t)p * D + ks * BK;
    float v[16];
    *(float4*)&v[0]  = *(const float4*)(s);
    *(float4*)&v[4]  = *(const float4*)(s + 4);
    *(float4*)&v[8]  = *(const float4*)(s + 8);
    *(float4*)&v[12] = *(const float4*)(s + 12);
    U4H8 a, b;
    #pragma unroll
    for (int j = 0; j < 8; j++) { a.h[j] = (_Float16)v[j]; b.h[j] = (_Float16)v[8 + j]; }
    size_t u = (size_t)ks * npts * 2 + (size_t)(p >> 5) * 64 + (p & 31);
    dst[u] = a.u; dst[u + 32] = b.u;
}

__global__ __launch_bounds__(256)
void row_norms_kernel(const float* __restrict__ X, const float* __restrict__ Y,
                      float* __restrict__ X2, float* __restrict__ Y2, int N, int M) {
    const int wave = threadIdx.x >> 6;
    const int lane = threadIdx.x & 63;
    const int row  = blockIdx.x * 4 + wave;
    const float* src; float* dst; int r;
    if (row < N)          { src = X; dst = X2; r = row; }
    else if (row < N + M) { src = Y; dst = Y2; r = row - N; }
    else return;
    const float* p = src + (size_t)r * D;
    float s = 0.f;
    #pragma unroll
    for (int c = 0; c < D; c += 64) {
        float v = p[c + lane];
        s = fmaf(v, v, s);
    }
    #pragma unroll
    for (int off = 32; off > 0; off >>= 1) s += __shfl_down(s, off);
    if (lane == 0) dst[r] = s;
}

__device__ inline unsigned float_key(float f) {
    unsigned u = __float_as_uint(f);
    return (u & 0x80000000u) ? ~u : (u | 0x80000000u);
}
__device__ inline float key_float(unsigned k) {
    return __uint_as_float((k & 0x80000000u) ? (k ^ 0x80000000u) : ~k);
}

// ---- XX/YY m: R5-bit-exact diag d2 via 32x32 self-tiles (fused X+Y) ------
__global__ __launch_bounds__(256)
void diag_min_bits_kernel(const float* __restrict__ X, const float* __restrict__ Y,
                          const float* __restrict__ X2, const float* __restrict__ Y2,
                          unsigned* __restrict__ minkey, int ngx) {
    int b = blockIdx.x;
    const float *src, *n2; int zidx;
    if (b < ngx) { src = X; n2 = X2; zidx = 0; }
    else         { src = Y; n2 = Y2; zidx = 2; b -= ngx; }

    const int tid  = threadIdx.x;
    const int wave = tid >> 6, lane = tid & 63;
    const int grp  = b * 4 + wave;                // 32-point group id
    const int fp   = lane & 31, fh = lane >> 5;
    const int pt   = grp * 32 + fp;
    const float* s = src + (size_t)pt * D + fh * 8;

    f32x16 acc;
    #pragma unroll
    for (int i = 0; i < 16; i++) acc[i] = 0.f;

    for (int ks = 0; ks < KSTEPS; ks++) {
        float v[8];
        *(float4*)&v[0] = *(const float4*)(s + ks * BK);
        *(float4*)&v[4] = *(const float4*)(s + ks * BK + 4);
        U4S8 hi, lo;
        split8(v, hi.u, lo.u);
        short8 ah = hi.s, al = lo.s;
        // R5 order: hh, h*lB, lA*h (A-frag == B-frag here)
        acc = __builtin_amdgcn_mfma_f32_32x32x16_bf16(ah, ah, acc, 0, 0, 0);
        acc = __builtin_amdgcn_mfma_f32_32x32x16_bf16(ah, al, acc, 0, 0, 0);
        acc = __builtin_amdgcn_mfma_f32_32x32x16_bf16(al, ah, acc, 0, 0, 0);
    }

    float dmin = 1e30f;
    if (fh == ((fp >> 2) & 1)) {
        int r = (fp & 3) + 4 * (fp >> 3);
        float av = acc[r];
        float rn = n2[pt];
        float cn = rn;
        float d2 = rn + cn - 2.0f * av;           // exact: contraction-safe
        dmin = d2;
    }
    #pragma unroll
    for (int off = 32; off > 0; off >>= 1) dmin = fminf(dmin, __shfl_down(dmin, off));
    __shared__ float wm[4];
    __shared__ int   wz[4];
    if (lane == 0) { wm[wave] = dmin; wz[wave] = zidx; }
    __syncthreads();
    if (tid == 0)
        atomicMin(&minkey[wz[0]],
                  float_key(fminf(fminf(wm[0], wm[1]), fminf(wm[2], wm[3]))));
}

// ---------- fp16 S-pass: grid (64,64,3): z=0 XX (sym), 1 XY, 2 YY ----------
// 128x128 block tile, 4 waves (2x2) of 64x64 -> acc[2][2]=64 regs ->
// 4 waves/SIMD at <=128 total regs. A+B DMA-staged; per 2-kstep buffer:
// [kstep j][A 256u | B 256u] (1024 uint4 = 16 KB); 2 bufs = 32 KB ->
// 4 blocks/CU. Each wave issues exactly 4 DMAs per stage -> vmcnt(4).
__global__ __launch_bounds__(256, 4)
void pair_exp_sum_kernel(const uint4* __restrict__ Xh, const uint4* __restrict__ Yh,
                         const float* __restrict__ X2, const float* __restrict__ Y2,
                         double* __restrict__ accum, float* __restrict__ bmin,
                         int N, int M) {
    const int z = blockIdx.z;
    const uint4 *Ah, *Bh; const float *An, *Bn; bool sym; int na, nb;
    if (z == 0)      { Ah = Xh; Bh = Xh; An = X2; Bn = X2; sym = true;  na = N; nb = N; }
    else if (z == 1) { Ah = Xh; Bh = Yh; An = X2; Bn = Y2; sym = false; na = N; nb = M; }
    else             { Ah = Yh; Bh = Yh; An = Y2; Bn = Y2; sym = true;  na = M; nb = M; }
    const int bi = blockIdx.x, bj = blockIdx.y;
    if (sym && bj < bi) return;                  // whole block below diagonal

    __shared__ uint4  smem[2][1024];             // 2 bufs x 16 KB (2 ksteps each)
    __shared__ float  smN[BTM + BTNP];
    __shared__ double wsum[4];
    __shared__ float  wmin[4];

    const int tid  = threadIdx.x;
    const int wave = tid >> 6, lane = tid & 63;
    const int wy = wave >> 1, wx = wave & 1;     // 2x2 waves, each 64x64
    const int row0 = bi * BTM, col0 = bj * BTNP;

    if (tid < BTM) smN[tid] = An[row0 + tid];
    else           smN[tid] = Bn[col0 + tid - BTM];

    const size_t strideA = (size_t)na * 2;       // 16B units per kstep
    const size_t strideB = (size_t)nb * 2;
    // stage-role of this wave: kstep-within-pair j, kind (0=A rows, 1=B cols)
    const int sj = wave >> 1, skind = wave & 1;
    const uint4* gS = (skind ? Bh + (size_t)(col0 >> 5) * 64
                             : Ah + (size_t)(row0 >> 5) * 64) + lane;
    const size_t strideS = skind ? strideB : strideA;

    f32x16 acc[2][2];
    #pragma unroll
    for (int g = 0; g < 2; g++)
        #pragma unroll
        for (int c = 0; c < 2; c++)
            #pragma unroll
            for (int i = 0; i < 16; i++) acc[g][c][i] = 0.f;

    // stage TWO k-steps into one buffer; kstep j at unit j*512: A@0, B@256.
    // Each wave loads its 256-unit chunk (4 x 64-unit segments) -> 4 DMAs.
    auto stage2 = [&](int buf, int ks) {
        const uint4* g = gS + (size_t)(ks + sj) * strideS;
        uint4* d = &smem[buf][sj * 512 + skind * 256 + lane];
        #pragma unroll
        for (int t = 0; t < 4; t++)
            lds16(g + t * 64, d + t * 64);
    };
    auto computeK = [&](const uint4* base) {     // one kstep: A@0, B@256
        const half8* p = (const half8*)base;
        half8 ah[2], bh[2];
        #pragma unroll
        for (int g = 0; g < 2; g++) ah[g] = p[(2 * wy + g) * 64 + lane];
        #pragma unroll
        for (int c = 0; c < 2; c++) bh[c] = p[256 + (2 * wx + c) * 64 + lane];
        #pragma unroll
        for (int g = 0; g < 2; g++)
            #pragma unroll
            for (int c = 0; c < 2; c++)
                acc[g][c] = __builtin_amdgcn_mfma_f32_32x32x16_f16(ah[g], bh[c], acc[g][c], 0, 0, 0);
    };

    // Counted-vmcnt schedule. Window invariant: each iteration issues exactly
    // 4 DMA ops per wave ("memory"-fenced) -> at s_waitcnt vmcnt(4) the
    // previous window's 4 are the FIFO-oldest outstanding, so they (and only
    // they) are drained. Current window's prefetch stays in flight across
    // both barriers.
    stage2(0, 0);

    #pragma unroll
    for (int it = 1; it < KSTEPS / 2; it++) {    // 15 intervals
        stage2(it & 1, 2 * it);                  // prefetch next pair (4 DMA)
        asm volatile("s_waitcnt vmcnt(4)" ::: "memory");    // prev pair landed (self)
        __builtin_amdgcn_s_barrier();                       // ... for all waves
        __builtin_amdgcn_sched_barrier(0);                  // pin ds_reads below
        const int pb = (it - 1) & 1;
        computeK(&smem[pb][0]);                  // ksteps 2(it-1), 2(it-1)+1
        computeK(&smem[pb][512]);
        asm volatile("s_waitcnt lgkmcnt(0)" ::: "memory");  // my ds_reads retired
        __builtin_amdgcn_s_barrier();                       // buffer pb free for all
    }
    asm volatile("s_waitcnt vmcnt(0)" ::: "memory");        // last pair landed
    __builtin_amdgcn_s_barrier();
    __builtin_amdgcn_sched_barrier(0);
    computeK(&smem[1][0]);                       // ksteps 30, 31
    computeK(&smem[1][512]);

    const float wgt = (sym && bj > bi) ? 2.f : 1.f;

    // C/D layout (m74/m101): col=lane&31, row=(reg&3)+8*(reg>>2)+4*(lane>>5)
    const int fp = lane & 31, fh = lane >> 5;
    double s = 0.0;
    float dmin = 1e30f;
    {
        const float* rowN = &smN[64 * wy];
        const float* colN = &smN[BTM + 64 * wx];
        const float kC = -0.0028177637517362567f;   // -log2(e)/512
        #pragma unroll
        for (int g = 0; g < 2; g++)
            #pragma unroll
            for (int c = 0; c < 2; c++) {
                float cn = colN[32 * c + fp];
                float rs = 0.f;
                #pragma unroll
                for (int r = 0; r < 16; r++) {
                    int r32 = (r & 3) + 8 * (r >> 2) + 4 * fh;
                    float d2 = rowN[32 * g + r32] + cn - 2.0f * acc[g][c][r];
                    dmin = fminf(dmin, d2);
                    rs += exp2f(d2 * kC);            // v_exp_f32; args in [-4.2,0]
                }
                s += (double)rs;
            }
        s *= (double)wgt;
    }

    #pragma unroll
    for (int off = 32; off > 0; off >>= 1) {
        s += __shfl_down(s, off);
        dmin = fminf(dmin, __shfl_down(dmin, off));
    }
    if (lane == 0) { wsum[wave] = s; wmin[wave] = dmin; }
    __syncthreads();
    if (tid == 0) {
        atomicAdd(&accum[z], wsum[0] + wsum[1] + wsum[2] + wsum[3]);
        if (z == 1)                              // noisy (+-~0.05) block min
            bmin[bi * gridDim.y + bj] = fminf(fminf(wmin[0], wmin[1]),
                                              fminf(wmin[2], wmin[3]));
    }
}

__global__ __launch_bounds__(256)
void xy_gmin_kernel(const float* __restrict__ bmin, float* __restrict__ gmin, int nblk) {
    float m = 1e30f;
    for (int i = threadIdx.x; i < nblk; i += 256) m = fminf(m, bmin[i]);
    #pragma unroll
    for (int off = 32; off > 0; off >>= 1) m = fminf(m, __shfl_down(m, off));
    __shared__ float wm[4];
    if ((threadIdx.x & 63) == 0) wm[threadIdx.x >> 6] = m;
    __syncthreads();
    if (threadIdx.x == 0) gmin[0] = fminf(fminf(wm[0], wm[1]), fminf(wm[2], wm[3]));
}

// ---------- XY refine: R5-bit-exact bf16-split 3-product d2 min -----------
// 1024 threads / 16 waves; wave w owns row-group gy=w&3 (32 rows) and col
// groups 2*(w>>2), 2*(w>>2)+1. Per-accumulator k-chain (hh,hl,lh per kstep,
// ks 0..31) identical to R5 -> same d2 bits; ~4x less serial latency.
// Gate: bmin now has 128-col granularity (nbj columns); this 256-col tile
// covers entries (bi, 2bj) and (bi, 2bj+1) -> gate on their min (identical
// decisions to the old 256-col bmin, which was the min over the same cells).
__global__ __launch_bounds__(1024)
void refine_min_kernel(const float* __restrict__ A, const float* __restrict__ B,
                       const float* __restrict__ An, const float* __restrict__ Bn,
                       const float* __restrict__ bmin, const float* __restrict__ gmin,
                       unsigned* __restrict__ minkey, int zidx, int nbj) {
    const int bi = blockIdx.x;
    const int bj = blockIdx.y;
    float bm = fminf(bmin[bi * nbj + 2 * bj], bmin[bi * nbj + 2 * bj + 1]);
    if (!(bm < gmin[0] + 0.5f)) return;
    const int row0 = bi * BTM, col0 = bj * BTN;

    __shared__ uint4 smem[1536];                 // Ahi|Alo|Bhi|Blo (R5 layout)
    __shared__ float smN[BTM + BTN];
    __shared__ float wmin[16];

    const int tid  = threadIdx.x;
    const int wave = tid >> 6, lane = tid & 63;
    const int gy = wave & 3, cg0 = 2 * (wave >> 2);
    if (tid < BTM) smN[tid] = An[row0 + tid];
    if (tid < BTN) smN[BTM + tid] = Bn[col0 + tid];

    const int fp = lane & 31, fh = lane >> 5;
    const int au = (32 * gy + fp) * 2 + fh;
    int bu[2];
    #pragma unroll
    for (int c = 0; c < 2; c++) bu[c] = (32 * (cg0 + c) + fp) * 2 + fh;

    f32x16 acc[2];
    #pragma unroll
    for (int c = 0; c < 2; c++)
        #pragma unroll
        for (int i = 0; i < 16; i++) acc[c][i] = 0.f;

    for (int ks = 0; ks < KSTEPS; ks++) {
        __syncthreads();                         // prev-step LDS reads done
        if (tid < 256) {                         // A: unit tid
            const float* s = A + (size_t)(row0 + (tid >> 1)) * D + ks * BK + (tid & 1) * 8;
            float v[8];
            *(float4*)&v[0] = *(const float4*)s;
            *(float4*)&v[4] = *(const float4*)(s + 4);
            uint4 hi, lo; split8(v, hi, lo);
            smem[AHI + tid] = hi; smem[ALO + tid] = lo;
        } else if (tid < 768) {                  // B: unit tid-256
            int u = tid - 256;
            const float* s = B + (size_t)(col0 + (u >> 1)) * D + ks * BK + (u & 1) * 8;
            float v[8];
            *(float4*)&v[0] = *(const float4*)s;
            *(float4*)&v[4] = *(const float4*)(s + 4);
            uint4 hi, lo; split8(v, hi, lo);
            smem[BHI + u] = hi; smem[BLO + u] = lo;
        }
        __syncthreads();
        {   // per-acc chain: hh, hl, lh (matches R5 acc[g][c] chain order)
            const short8* p = (const short8*)&smem[0];
            short8 ah = p[AHI + au], al = p[ALO + au];
            short8 bh[2], bl[2];
            #pragma unroll
            for (int c = 0; c < 2; c++) { bh[c] = p[BHI + bu[c]]; bl[c] = p[BLO + bu[c]]; }
            #pragma unroll
            for (int c = 0; c < 2; c++)
                acc[c] = __builtin_amdgcn_mfma_f32_32x32x16_bf16(ah, bh[c], acc[c], 0, 0, 0);
            #pragma unroll
            for (int c = 0; c < 2; c++)
                acc[c] = __builtin_amdgcn_mfma_f32_32x32x16_bf16(ah, bl[c], acc[c], 0, 0, 0);
            #pragma unroll
            for (int c = 0; c < 2; c++)
                acc[c] = __builtin_amdgcn_mfma_f32_32x32x16_bf16(al, bh[c], acc[c], 0, 0, 0);
        }
    }

    float dmin = 1e30f;
    const float* rowN = &smN[32 * gy];
    #pragma unroll
    for (int c = 0; c < 2; c++) {
        float cn = smN[BTM + 32 * (cg0 + c) + fp];
        #pragma unroll
        for (int r = 0; r < 16; r++) {
            int r32 = (r & 3) + 8 * (r >> 2) + 4 * fh;
            float d2 = rowN[r32] + cn - 2.0f * acc[c][r];
            dmin = fminf(dmin, d2);
        }
    }

    #pragma unroll
    for (int off = 32; off > 0; off >>= 1) dmin = fminf(dmin, __shfl_down(dmin, off));
    if (lane == 0) wmin[wave] = dmin;
    __syncthreads();
    if (tid == 0) {
        float m = wmin[0];
        #pragma unroll
        for (int w = 1; w < 16; w++) m = fminf(m, wmin[w]);
        atomicMin(&minkey[zidx], float_key(m));
    }
}

__global__ void finalize_kernel(const double* __restrict__ accum,
                                const unsigned* __restrict__ minkey,
                                float* __restrict__ out, int N, int M) {
    if (threadIdx.x == 0 && blockIdx.x == 0) {
        float Sp[3];
        #pragma unroll
        for (int z = 0; z < 3; z++) {
            float m = key_float(minkey[z]) * (-1.0f / 512.0f);
            double Sshift = accum[z] * exp(-(double)m);
            float r = (float)log(Sshift);        // correctly-rounded f32 log
            float lse = r + m;                   // fp32 add, as jax
            Sp[z] = (float)exp((double)lse);     // correctly-rounded f32 exp
        }
        float nf  = (float)N, mf = (float)M;
        float nn1 = (float)((double)N * (double)(N - 1));
        float mm1 = (float)((double)M * (double)(M - 1));
        float nm  = (float)((double)N * (double)M);
        float xx = (Sp[0] - nf) / nn1;
        float xy =  Sp[1]       / nm;
        float yy = (Sp[2] - mf) / mm1;
        out[0] = xx - 2.0f * xy + yy;
    }
}

extern "C" void kernel_launch(void* const* d_in, const int* in_sizes, int n_in,
                              void* d_out, int out_size, void* d_ws, size_t ws_size,
                              hipStream_t stream) {
    const float* X = (const float*)d_in[0];
    const float* Y = (const float*)d_in[1];
    const int N = in_sizes[0] / D;
    const int M = in_sizes[1] / D;
    const int gx  = N / BTM;                     // 64
    const int gyP = M / BTNP;                    // 64 (pair kernel cols)
    const int gyR = M / BTN;                     // 32 (refine cols)

    double*   accum  = (double*)d_ws;
    unsigned* minkey = (unsigned*)((char*)d_ws + 32);
    float*    gmin   = (float*)((char*)d_ws + 48);
    float*    X2     = (float*)((char*)d_ws + 64);
    float*    Y2     = X2 + N;
    float*    bmin   = Y2 + M;
    size_t off = (64 + (size_t)(N + M) * 4 + (size_t)gx * gyP * 4 + 255) & ~(size_t)255;
    size_t asz = (size_t)N * D * 2;
    uint4* Xh = (uint4*)((char*)d_ws + off);
    uint4* Yh = (uint4*)((char*)d_ws + off + asz);

    init_kernel<<<1, 64, 0, stream>>>(accum, minkey);

    row_norms_kernel<<<(N + M + 3) / 4, 256, 0, stream>>>(X, Y, X2, Y2, N, M);
    convert_h_kernel<<<dim3((N + 255) / 256, KSTEPS, 2), 256, 0, stream>>>(X, Y, Xh, Yh, N);

    diag_min_bits_kernel<<<N / 128 + M / 128, 256, 0, stream>>>(X, Y, X2, Y2, minkey, N / 128);

    dim3 grid(gx, gyP, 3);
    pair_exp_sum_kernel<<<grid, 256, 0, stream>>>(Xh, Yh, X2, Y2, accum, bmin, N, M);

    xy_gmin_kernel<<<1, 256, 0, stream>>>(bmin, gmin, gx * gyP);
    refine_min_kernel<<<dim3(gx, gyR), 1024, 0, stream>>>(X, Y, X2, Y2, bmin, gmin,
                                                          minkey, 1, gyP);

    finalize_kernel<<<1, 64, 0, stream>>>(accum, minkey, (float*)d_out, N, M);
}

// Round 7
// 307.063 us; speedup vs baseline: 2.5593x; 1.0284x over previous
//
#include <hip/hip_runtime.h>
#include <math.h>

// MMD, Gaussian kernel, bandwidth=512. X:[8192,512] Y:[8192,512] fp32.
// S_AB = sum_ij exp(-||a_i-b_j||^2/512); final combine emulates the
// reference's fp32 logsumexp->exp->combine path (see finalize_kernel).
//
// Architecture (validated R9-R11): fp16 single-product MFMA S-pass (S needs
// << 1 fp32 lse cell = 17 units of 9.1e6) + bit-exact reproduction of the
// R5 bf16-split 3-product d2 min for m (XX/YY via 32x32 diag self-tiles,
// XY via banded refine).
// Round-15 (PASSED, 180us): 128x128 tiles, 4 waves of 64x64, A+B DMA-staged,
// 2-kstep dbuf, 2 barriers + vmcnt + lgkm(0) per interval. MfmaUtil 37%.
// Round-16/17 FAILED (NaN): A-frags via register loads mixed with LDS-DMA
// in one counted-vmcnt window. vmcnt completion order across op CLASSES is
// not guaranteed -> vmcnt(6) can retire reg-loads while a prev-window DMA
// is in flight -> stale LDS read. RULE: counted-vmcnt windows must be
// homogeneous. (R13 "passed" only because its 7000cy interval hid the race.)
// Round-18: all-DMA data path restored (R15's, proven); overhead attacked
// structurally: 3-buffer single-barrier pipeline. Per interval:
// {vmcnt(4); s_barrier; stage window t+2; compute window t}. One barrier
// per 2 ksteps (was 2), prefetch depth 2 intervals (covers L2/HBM latency),
// homogeneous DMA FIFO makes vmcnt(4) provably drain window t. Buffer-reuse
// safe: reads of buf b at iter t-1 retire before that wave's MFMAs, hence
// before barrier t; stage of buf b reissues only after barrier t.
// K-steps 0..31 sequential, per-kstep MFMA order unchanged -> bit-identical.
// Round-19: identical resubmit of Round-18 - the R18 bench died with
// "MI355X container failed twice" (infra, no test/rocprof output). Kernel
// audited for hang risk: uniform barriers, terminating vmcnt ledger,
// homogeneous DMA windows -> resubmit unchanged to keep attribution clean.

#define D      512
#define BTM    128
#define BTN    256   // refine-kernel tile (unchanged)
#define BTNP   128   // pair-kernel tile cols
#define BK     16
#define KSTEPS (D / BK)

// 16B-unit offsets in the XY refine kernel's LDS (R5 layout [point*2+khalf])
#define AHI 0
#define ALO 256
#define BHI 512
#define BLO 1024

typedef _Float16 half8 __attribute__((ext_vector_type(8)));
typedef __attribute__((ext_vector_type(8)))  short  short8;   // 8 bf16
typedef __attribute__((ext_vector_type(16))) float  f32x16;   // 32x32 acc

union U4H8 { uint4 u; half8 h; };
union U4S8 { uint4 u; short8 s; };

__device__ __forceinline__ unsigned short bf16_rne(float x) {
    unsigned u = __float_as_uint(x);
    return (unsigned short)((u + 0x7fffu + ((u >> 16) & 1u)) >> 16);
}
__device__ __forceinline__ float bf16_f32(unsigned short b) {
    return __uint_as_float(((unsigned)b) << 16);
}
__device__ __forceinline__ void split8(const float v[8], uint4& hi, uint4& lo) {
    unsigned h[8], l[8];
    #pragma unroll
    for (int j = 0; j < 8; j++) {
        unsigned short bh = bf16_rne(v[j]);
        float r = v[j] - bf16_f32(bh);          // exact (Sterbenz)
        unsigned short bl = bf16_rne(r);
        h[j] = bh; l[j] = bl;
    }
    hi.x = h[0] | (h[1] << 16); hi.y = h[2] | (h[3] << 16);
    hi.z = h[4] | (h[5] << 16); hi.w = h[6] | (h[7] << 16);
    lo.x = l[0] | (l[1] << 16); lo.y = l[2] | (l[3] << 16);
    lo.z = l[4] | (l[5] << 16); lo.w = l[6] | (l[7] << 16);
}

// async global->LDS, 16B per lane
__device__ __forceinline__ void lds16(const uint4* g, uint4* l) {
    __builtin_amdgcn_global_load_lds(
        (const __attribute__((address_space(1))) void*)g,
        (__attribute__((address_space(3))) void*)(unsigned int)(uintptr_t)(void*)l,
        16, 0, 0);
}

__global__ void init_kernel(double* accum, unsigned* minkey) {
    if (threadIdx.x < 3) accum[threadIdx.x] = 0.0;
    if (threadIdx.x < 4) minkey[threadIdx.x] = 0xFFFFFFFFu;
}

// fp16 convert: src[npts][512] fp32 -> [kstep][p>>5][khalf][p&31] 16B units
__global__ __launch_bounds__(256)
void convert_h_kernel(const float* __restrict__ X, const float* __restrict__ Y,
                      uint4* __restrict__ Xh, uint4* __restrict__ Yh, int npts) {
    const float* src = blockIdx.z ? Y : X;
    uint4*       dst = blockIdx.z ? Yh : Xh;
    const int ks = blockIdx.y;
    const int p  = blockIdx.x * 256 + threadIdx.x;
    if (p >= npts) return;
    const float* s = src + (size_t)p * D + ks * BK;
    float v[16];
    *(float4*)&v[0]  = *(const float4*)(s);
    *(float4*)&v[4]  = *(const float4*)(s + 4);
    *(float4*)&v[8]  = *(const float4*)(s + 8);
    *(float4*)&v[12] = *(const float4*)(s + 12);
    U4H8 a, b;
    #pragma unroll
    for (int j = 0; j < 8; j++) { a.h[j] = (_Float16)v[j]; b.h[j] = (_Float16)v[8 + j]; }
    size_t u = (size_t)ks * npts * 2 + (size_t)(p >> 5) * 64 + (p & 31);
    dst[u] = a.u; dst[u + 32] = b.u;
}

__global__ __launch_bounds__(256)
void row_norms_kernel(const float* __restrict__ X, const float* __restrict__ Y,
                      float* __restrict__ X2, float* __restrict__ Y2, int N, int M) {
    const int wave = threadIdx.x >> 6;
    const int lane = threadIdx.x & 63;
    const int row  = blockIdx.x * 4 + wave;
    const float* src; float* dst; int r;
    if (row < N)          { src = X; dst = X2; r = row; }
    else if (row < N + M) { src = Y; dst = Y2; r = row - N; }
    else return;
    const float* p = src + (size_t)r * D;
    float s = 0.f;
    #pragma unroll
    for (int c = 0; c < D; c += 64) {
        float v = p[c + lane];
        s = fmaf(v, v, s);
    }
    #pragma unroll
    for (int off = 32; off > 0; off >>= 1) s += __shfl_down(s, off);
    if (lane == 0) dst[r] = s;
}

__device__ inline unsigned float_key(float f) {
    unsigned u = __float_as_uint(f);
    return (u & 0x80000000u) ? ~u : (u | 0x80000000u);
}
__device__ inline float key_float(unsigned k) {
    return __uint_as_float((k & 0x80000000u) ? (k ^ 0x80000000u) : ~k);
}

// ---- XX/YY m: R5-bit-exact diag d2 via 32x32 self-tiles (fused X+Y) ------
__global__ __launch_bounds__(256)
void diag_min_bits_kernel(const float* __restrict__ X, const float* __restrict__ Y,
                          const float* __restrict__ X2, const float* __restrict__ Y2,
                          unsigned* __restrict__ minkey, int ngx) {
    int b = blockIdx.x;
    const float *src, *n2; int zidx;
    if (b < ngx) { src = X; n2 = X2; zidx = 0; }
    else         { src = Y; n2 = Y2; zidx = 2; b -= ngx; }

    const int tid  = threadIdx.x;
    const int wave = tid >> 6, lane = tid & 63;
    const int grp  = b * 4 + wave;                // 32-point group id
    const int fp   = lane & 31, fh = lane >> 5;
    const int pt   = grp * 32 + fp;
    const float* s = src + (size_t)pt * D + fh * 8;

    f32x16 acc;
    #pragma unroll
    for (int i = 0; i < 16; i++) acc[i] = 0.f;

    for (int ks = 0; ks < KSTEPS; ks++) {
        float v[8];
        *(float4*)&v[0] = *(const float4*)(s + ks * BK);
        *(float4*)&v[4] = *(const float4*)(s + ks * BK + 4);
        U4S8 hi, lo;
        split8(v, hi.u, lo.u);
        short8 ah = hi.s, al = lo.s;
        // R5 order: hh, h*lB, lA*h (A-frag == B-frag here)
        acc = __builtin_amdgcn_mfma_f32_32x32x16_bf16(ah, ah, acc, 0, 0, 0);
        acc = __builtin_amdgcn_mfma_f32_32x32x16_bf16(ah, al, acc, 0, 0, 0);
        acc = __builtin_amdgcn_mfma_f32_32x32x16_bf16(al, ah, acc, 0, 0, 0);
    }

    float dmin = 1e30f;
    if (fh == ((fp >> 2) & 1)) {
        int r = (fp & 3) + 4 * (fp >> 3);
        float av = acc[r];
        float rn = n2[pt];
        float cn = rn;
        float d2 = rn + cn - 2.0f * av;           // exact: contraction-safe
        dmin = d2;
    }
    #pragma unroll
    for (int off = 32; off > 0; off >>= 1) dmin = fminf(dmin, __shfl_down(dmin, off));
    __shared__ float wm[4];
    __shared__ int   wz[4];
    if (lane == 0) { wm[wave] = dmin; wz[wave] = zidx; }
    __syncthreads();
    if (tid == 0)
        atomicMin(&minkey[wz[0]],
                  float_key(fminf(fminf(wm[0], wm[1]), fminf(wm[2], wm[3]))));
}

// ---------- fp16 S-pass: grid (64,64,3): z=0 XX (sym), 1 XY, 2 YY ----------
// 128x128 block tile, 4 waves (2x2) of 64x64. A+B DMA-staged (homogeneous
// window, in-order FIFO). THREE 16KB buffers (window = 2 ksteps, each kstep
// [A 256u | B 256u]), single barrier per interval:
//   { vmcnt(4): window t landed ; s_barrier ; stage window t+2 ; compute t }
// Prefetch depth 2 intervals covers L2/HBM latency. Each wave stages 256
// units (kstep sj, kind skind) = 4 DMAs -> vmcnt(4).
__global__ __launch_bounds__(256, 2)
void pair_exp_sum_kernel(const uint4* __restrict__ Xh, const uint4* __restrict__ Yh,
                         const float* __restrict__ X2, const float* __restrict__ Y2,
                         double* __restrict__ accum, float* __restrict__ bmin,
                         int N, int M) {
    const int z = blockIdx.z;
    const uint4 *Ah, *Bh; const float *An, *Bn; bool sym; int na, nb;
    if (z == 0)      { Ah = Xh; Bh = Xh; An = X2; Bn = X2; sym = true;  na = N; nb = N; }
    else if (z == 1) { Ah = Xh; Bh = Yh; An = X2; Bn = Y2; sym = false; na = N; nb = M; }
    else             { Ah = Yh; Bh = Yh; An = Y2; Bn = Y2; sym = true;  na = M; nb = M; }
    const int bi = blockIdx.x, bj = blockIdx.y;
    if (sym && bj < bi) return;                  // whole block below diagonal

    __shared__ uint4  smem[3][1024];             // 3 bufs x 16 KB (2 ksteps each)
    __shared__ float  smN[BTM + BTNP];
    __shared__ double wsum[4];
    __shared__ float  wmin[4];

    const int tid  = threadIdx.x;
    const int wave = tid >> 6, lane = tid & 63;
    const int wy = wave >> 1, wx = wave & 1;     // 2x2 waves, each 64x64
    const int row0 = bi * BTM, col0 = bj * BTNP;

    if (tid < BTM) smN[tid] = An[row0 + tid];
    else           smN[tid] = Bn[col0 + tid - BTM];

    const size_t strideA = (size_t)na * 2;       // 16B units per kstep
    const size_t strideB = (size_t)nb * 2;
    // stage-role of this wave: kstep-within-window sj, kind (0=A rows, 1=B cols)
    const int sj = wave >> 1, skind = wave & 1;
    const uint4* gS = (skind ? Bh + (size_t)(col0 >> 5) * 64
                             : Ah + (size_t)(row0 >> 5) * 64) + lane;
    const size_t strideS = skind ? strideB : strideA;

    f32x16 acc[2][2];
    #pragma unroll
    for (int g = 0; g < 2; g++)
        #pragma unroll
        for (int c = 0; c < 2; c++)
            #pragma unroll
            for (int i = 0; i < 16; i++) acc[g][c][i] = 0.f;

    // stage one 2-kstep window into buffer buf; kstep j at unit j*512: A@0, B@256.
    // This wave loads the 256-unit chunk (kstep sj, kind skind) = 4 DMAs.
    auto stage2 = [&](int buf, int ks) {
        const uint4* g = gS + (size_t)(ks + sj) * strideS;
        uint4* d = &smem[buf][sj * 512 + skind * 256 + lane];
        #pragma unroll
        for (int t = 0; t < 4; t++)
            lds16(g + t * 64, d + t * 64);
    };
    auto computeK = [&](const uint4* base) {     // one kstep: A@0, B@256
        const half8* p = (const half8*)base;
        half8 ah[2], bh[2];
        #pragma unroll
        for (int g = 0; g < 2; g++) ah[g] = p[(2 * wy + g) * 64 + lane];
        #pragma unroll
        for (int c = 0; c < 2; c++) bh[c] = p[256 + (2 * wx + c) * 64 + lane];
        #pragma unroll
        for (int g = 0; g < 2; g++)
            #pragma unroll
            for (int c = 0; c < 2; c++)
                acc[g][c] = __builtin_amdgcn_mfma_f32_32x32x16_f16(ah[g], bh[c], acc[g][c], 0, 0, 0);
    };

    // 16 windows of 2 ksteps; windows 0,1 prefetched in the prologue.
    stage2(0, 0);                                // window 0 (ksteps 0,1)
    stage2(1, 2);                                // window 1 (ksteps 2,3)

    #pragma unroll
    for (int t = 0; t < 14; t++) {
        asm volatile("s_waitcnt vmcnt(4)" ::: "memory");    // window t landed (self)
        __builtin_amdgcn_s_barrier();                       // ... for all waves; and
                                                            // all reads of buf (t+2)%3 are done
        __builtin_amdgcn_sched_barrier(0);                  // pin everything below
        stage2((t + 2) % 3, 2 * (t + 2));        // refill freed buffer (4 DMA)
        const uint4* cb = &smem[t % 3][0];
        computeK(cb);                            // kstep 2t
        computeK(cb + 512);                      // kstep 2t+1
    }
    asm volatile("s_waitcnt vmcnt(4)" ::: "memory");        // window 14 landed
    __builtin_amdgcn_s_barrier();
    __builtin_amdgcn_sched_barrier(0);
    computeK(&smem[2][0]);                       // ksteps 28,29  (14%3==2)
    computeK(&smem[2][512]);
    asm volatile("s_waitcnt vmcnt(0)" ::: "memory");        // window 15 landed
    __builtin_amdgcn_s_barrier();
    __builtin_amdgcn_sched_barrier(0);
    computeK(&smem[0][0]);                       // ksteps 30,31  (15%3==0)
    computeK(&smem[0][512]);

    const float wgt = (sym && bj > bi) ? 2.f : 1.f;

    // C/D layout (m74/m101): col=lane&31, row=(reg&3)+8*(reg>>2)+4*(lane>>5)
    const int fp = lane & 31, fh = lane >> 5;
    double s = 0.0;
    float dmin = 1e30f;
    {
        const float* rowN = &smN[64 * wy];
        const float* colN = &smN[BTM + 64 * wx];
        const float kC = -0.0028177637517362567f;   // -log2(e)/512
        #pragma unroll
        for (int g = 0; g < 2; g++)
            #pragma unroll
            for (int c = 0; c < 2; c++) {
                float cn = colN[32 * c + fp];
                float rs = 0.f;
                #pragma unroll
                for (int r = 0; r < 16; r++) {
                    int r32 = (r & 3) + 8 * (r >> 2) + 4 * fh;
                    float d2 = rowN[32 * g + r32] + cn - 2.0f * acc[g][c][r];
                    dmin = fminf(dmin, d2);
                    rs += exp2f(d2 * kC);            // v_exp_f32; args in [-4.2,0]
                }
                s += (double)rs;
            }
        s *= (double)wgt;
    }

    #pragma unroll
    for (int off = 32; off > 0; off >>= 1) {
        s += __shfl_down(s, off);
        dmin = fminf(dmin, __shfl_down(dmin, off));
    }
    if (lane == 0) { wsum[wave] = s; wmin[wave] = dmin; }
    __syncthreads();
    if (tid == 0) {
        atomicAdd(&accum[z], wsum[0] + wsum[1] + wsum[2] + wsum[3]);
        if (z == 1)                              // noisy (+-~0.05) block min
            bmin[bi * gridDim.y + bj] = fminf(fminf(wmin[0], wmin[1]),
                                              fminf(wmin[2], wmin[3]));
    }
}

__global__ __launch_bounds__(256)
void xy_gmin_kernel(const float* __restrict__ bmin, float* __restrict__ gmin, int nblk) {
    float m = 1e30f;
    for (int i = threadIdx.x; i < nblk; i += 256) m = fminf(m, bmin[i]);
    #pragma unroll
    for (int off = 32; off > 0; off >>= 1) m = fminf(m, __shfl_down(m, off));
    __shared__ float wm[4];
    if ((threadIdx.x & 63) == 0) wm[threadIdx.x >> 6] = m;
    __syncthreads();
    if (threadIdx.x == 0) gmin[0] = fminf(fminf(wm[0], wm[1]), fminf(wm[2], wm[3]));
}

// ---------- XY refine: R5-bit-exact bf16-split 3-product d2 min -----------
// 1024 threads / 16 waves; wave w owns row-group gy=w&3 (32 rows) and col
// groups 2*(w>>2), 2*(w>>2)+1. Per-accumulator k-chain (hh,hl,lh per kstep,
// ks 0..31) identical to R5 -> same d2 bits; ~4x less serial latency.
// Gate: bmin has 128-col granularity (nbj columns); this 256-col tile
// covers entries (bi, 2bj) and (bi, 2bj+1) -> gate on their min (identical
// decisions to the old 256-col bmin, which was the min over the same cells).
__global__ __launch_bounds__(1024)
void refine_min_kernel(const float* __restrict__ A, const float* __restrict__ B,
                       const float* __restrict__ An, const float* __restrict__ Bn,
                       const float* __restrict__ bmin, const float* __restrict__ gmin,
                       unsigned* __restrict__ minkey, int zidx, int nbj) {
    const int bi = blockIdx.x;
    const int bj = blockIdx.y;
    float bm = fminf(bmin[bi * nbj + 2 * bj], bmin[bi * nbj + 2 * bj + 1]);
    if (!(bm < gmin[0] + 0.5f)) return;
    const int row0 = bi * BTM, col0 = bj * BTN;

    __shared__ uint4 smem[1536];                 // Ahi|Alo|Bhi|Blo (R5 layout)
    __shared__ float smN[BTM + BTN];
    __shared__ float wmin[16];

    const int tid  = threadIdx.x;
    const int wave = tid >> 6, lane = tid & 63;
    const int gy = wave & 3, cg0 = 2 * (wave >> 2);
    if (tid < BTM) smN[tid] = An[row0 + tid];
    if (tid < BTN) smN[BTM + tid] = Bn[col0 + tid];

    const int fp = lane & 31, fh = lane >> 5;
    const int au = (32 * gy + fp) * 2 + fh;
    int bu[2];
    #pragma unroll
    for (int c = 0; c < 2; c++) bu[c] = (32 * (cg0 + c) + fp) * 2 + fh;

    f32x16 acc[2];
    #pragma unroll
    for (int c = 0; c < 2; c++)
        #pragma unroll
        for (int i = 0; i < 16; i++) acc[c][i] = 0.f;

    for (int ks = 0; ks < KSTEPS; ks++) {
        __syncthreads();                         // prev-step LDS reads done
        if (tid < 256) {                         // A: unit tid
            const float* s = A + (size_t)(row0 + (tid >> 1)) * D + ks * BK + (tid & 1) * 8;
            float v[8];
            *(float4*)&v[0] = *(const float4*)s;
            *(float4*)&v[4] = *(const float4*)(s + 4);
            uint4 hi, lo; split8(v, hi, lo);
            smem[AHI + tid] = hi; smem[ALO + tid] = lo;
        } else if (tid < 768) {                  // B: unit tid-256
            int u = tid - 256;
            const float* s = B + (size_t)(col0 + (u >> 1)) * D + ks * BK + (u & 1) * 8;
            float v[8];
            *(float4*)&v[0] = *(const float4*)s;
            *(float4*)&v[4] = *(const float4*)(s + 4);
            uint4 hi, lo; split8(v, hi, lo);
            smem[BHI + u] = hi; smem[BLO + u] = lo;
        }
        __syncthreads();
        {   // per-acc chain: hh, hl, lh (matches R5 acc[g][c] chain order)
            const short8* p = (const short8*)&smem[0];
            short8 ah = p[AHI + au], al = p[ALO + au];
            short8 bh[2], bl[2];
            #pragma unroll
            for (int c = 0; c < 2; c++) { bh[c] = p[BHI + bu[c]]; bl[c] = p[BLO + bu[c]]; }
            #pragma unroll
            for (int c = 0; c < 2; c++)
                acc[c] = __builtin_amdgcn_mfma_f32_32x32x16_bf16(ah, bh[c], acc[c], 0, 0, 0);
            #pragma unroll
            for (int c = 0; c < 2; c++)
                acc[c] = __builtin_amdgcn_mfma_f32_32x32x16_bf16(ah, bl[c], acc[c], 0, 0, 0);
            #pragma unroll
            for (int c = 0; c < 2; c++)
                acc[c] = __builtin_amdgcn_mfma_f32_32x32x16_bf16(al, bh[c], acc[c], 0, 0, 0);
        }
    }

    float dmin = 1e30f;
    const float* rowN = &smN[32 * gy];
    #pragma unroll
    for (int c = 0; c < 2; c++) {
        float cn = smN[BTM + 32 * (cg0 + c) + fp];
        #pragma unroll
        for (int r = 0; r < 16; r++) {
            int r32 = (r & 3) + 8 * (r >> 2) + 4 * fh;
            float d2 = rowN[r32] + cn - 2.0f * acc[c][r];
            dmin = fminf(dmin, d2);
        }
    }

    #pragma unroll
    for (int off = 32; off > 0; off >>= 1) dmin = fminf(dmin, __shfl_down(dmin, off));
    if (lane == 0) wmin[wave] = dmin;
    __syncthreads();
    if (tid == 0) {
        float m = wmin[0];
        #pragma unroll
        for (int w = 1; w < 16; w++) m = fminf(m, wmin[w]);
        atomicMin(&minkey[zidx], float_key(m));
    }
}

__global__ void finalize_kernel(const double* __restrict__ accum,
                                const unsigned* __restrict__ minkey,
                                float* __restrict__ out, int N, int M) {
    if (threadIdx.x == 0 && blockIdx.x == 0) {
        float Sp[3];
        #pragma unroll
        for (int z = 0; z < 3; z++) {
            float m = key_float(minkey[z]) * (-1.0f / 512.0f);
            double Sshift = accum[z] * exp(-(double)m);
            float r = (float)log(Sshift);        // correctly-rounded f32 log
            float lse = r + m;                   // fp32 add, as jax
            Sp[z] = (float)exp((double)lse);     // correctly-rounded f32 exp
        }
        float nf  = (float)N, mf = (float)M;
        float nn1 = (float)((double)N * (double)(N - 1));
        float mm1 = (float)((double)M * (double)(M - 1));
        float nm  = (float)((double)N * (double)M);
        float xx = (Sp[0] - nf) / nn1;
        float xy =  Sp[1]       / nm;
        float yy = (Sp[2] - mf) / mm1;
        out[0] = xx - 2.0f * xy + yy;
    }
}

extern "C" void kernel_launch(void* const* d_in, const int* in_sizes, int n_in,
                              void* d_out, int out_size, void* d_ws, size_t ws_size,
                              hipStream_t stream) {
    const float* X = (const float*)d_in[0];
    const float* Y = (const float*)d_in[1];
    const int N = in_sizes[0] / D;
    const int M = in_sizes[1] / D;
    const int gx  = N / BTM;                     // 64
    const int gyP = M / BTNP;                    // 64 (pair kernel cols)
    const int gyR = M / BTN;                     // 32 (refine cols)

    double*   accum  = (double*)d_ws;
    unsigned* minkey = (unsigned*)((char*)d_ws + 32);
    float*    gmin   = (float*)((char*)d_ws + 48);
    float*    X2     = (float*)((char*)d_ws + 64);
    float*    Y2     = X2 + N;
    float*    bmin   = Y2 + M;
    size_t off = (64 + (size_t)(N + M) * 4 + (size_t)gx * gyP * 4 + 255) & ~(size_t)255;
    size_t asz = (size_t)N * D * 2;
    uint4* Xh = (uint4*)((char*)d_ws + off);
    uint4* Yh = (uint4*)((char*)d_ws + off + asz);

    init_kernel<<<1, 64, 0, stream>>>(accum, minkey);

    row_norms_kernel<<<(N + M + 3) / 4, 256, 0, stream>>>(X, Y, X2, Y2, N, M);
    convert_h_kernel<<<dim3((N + 255) / 256, KSTEPS, 2), 256, 0, stream>>>(X, Y, Xh, Yh, N);

    diag_min_bits_kernel<<<N / 128 + M / 128, 256, 0, stream>>>(X, Y, X2, Y2, minkey, N / 128);

    dim3 grid(gx, gyP, 3);
    pair_exp_sum_kernel<<<grid, 256, 0, stream>>>(Xh, Yh, X2, Y2, accum, bmin, N, M);

    xy_gmin_kernel<<<1, 256, 0, stream>>>(bmin, gmin, gx * gyP);
    refine_min_kernel<<<dim3(gx, gyR), 1024, 0, stream>>>(X, Y, X2, Y2, bmin, gmin,
                                                          minkey, 1, gyP);

    finalize_kernel<<<1, 64, 0, stream>>>(accum, minkey, (float*)d_out, N, M);
}